// Round 12
// baseline (740.899 us; speedup 1.0000x reference)
//
#include <hip/hip_runtime.h>
#include <hip/hip_fp16.h>

#define HID 32
#define BN_EPS 1e-5f
#define NBMAX 512
#define BSHIFT 9
#define SCAT_CH 8192
#define FSTRIDE 10240
#define FCAP 10240
#define DP_CH 4096

static __device__ __forceinline__ int lbound(const int* a, int n, int key) {
    int lo = 0, hi = n;
    while (lo < hi) { int m = (lo + hi) >> 1; if (a[m] < key) lo = m + 1; else hi = m; }
    return lo;
}

static __device__ __forceinline__ unsigned packh2(float a, float b) {
    __half2 h = __floats2half2_rn(a, b);
    return *reinterpret_cast<unsigned*>(&h);
}
static __device__ __forceinline__ float lo_h(unsigned v) {
    __half2 h = *reinterpret_cast<__half2*>(&v);
    return __low2float(h);
}
static __device__ __forceinline__ float hi_h(unsigned v) {
    __half2 h = *reinterpret_cast<__half2*>(&v);
    return __high2float(h);
}
static __device__ __forceinline__ float h2f(unsigned short v) {
    return __half2float(__ushort_as_half(v));
}

// non-temporal 16B load (keeps streamed gather rows from evicting L1-hot weights)
static __device__ __forceinline__ uint4 ldnt4(const uint4* p) {
#if defined(__has_builtin)
#if __has_builtin(__builtin_nontemporal_load)
    typedef unsigned int uv4 __attribute__((ext_vector_type(4)));
    uv4 v = __builtin_nontemporal_load((const uv4*)p);
    return make_uint4(v[0], v[1], v[2], v[3]);
#else
    return *p;
#endif
#else
    return *p;
#endif
}

static __device__ __forceinline__ void addu4h(float* a, uint4 v) {
    a[0] += lo_h(v.x); a[1] += hi_h(v.x);
    a[2] += lo_h(v.y); a[3] += hi_h(v.y);
    a[4] += lo_h(v.z); a[5] += hi_h(v.z);
    a[6] += lo_h(v.w); a[7] += hi_h(v.w);
}

// ---------------- bucketed CSR build ----------------
__global__ void __launch_bounds__(256) k_bscatter(const int* __restrict__ ei,
                                                  int* __restrict__ gcur,
                                                  int* __restrict__ pairs, int E, int NB) {
    __shared__ int h[NBMAX];
    __shared__ int lb[NBMAX];
    int t = threadIdx.x;
    int c0 = blockIdx.x * SCAT_CH;
    int end = min(c0 + SCAT_CH, E);
    for (int i = t; i < NBMAX; i += 256) h[i] = 0;
    __syncthreads();
    for (int i = c0 + t; i < end; i += 256)
        atomicAdd(&h[ei[E + i] >> BSHIFT], 1);
    __syncthreads();
    for (int b = t; b < NB; b += 256) {
        int c = h[b];
        lb[b] = c ? atomicAdd(&gcur[b], c) : 0;
        h[b] = 0;
    }
    __syncthreads();
    for (int i = c0 + t; i < end; i += 256) {
        int src = ei[i], d = ei[E + i];
        int bkt = d >> BSHIFT;
        int r = atomicAdd(&h[bkt], 1);
        pairs[bkt * FSTRIDE + lb[bkt] + r] = src | ((d & 511) << 18);
    }
}

__global__ void __launch_bounds__(512) k_bscan(const int* __restrict__ gcur,
                                               int* __restrict__ bbase,
                                               int* __restrict__ rowstart,
                                               int N, int E, int NB) {
    __shared__ int s[512];
    int t = threadIdx.x;
    int v = (t < NB) ? gcur[t] : 0;
    s[t] = v; __syncthreads();
    for (int off = 1; off < 512; off <<= 1) {
        int u = (t >= off) ? s[t - off] : 0; __syncthreads();
        s[t] += u; __syncthreads();
    }
    int excl = s[t] - v;
    if (t < NB) bbase[t] = excl;
    if (t == NB - 1) bbase[NB] = s[t];
    if (t == 0) rowstart[N] = E;
}

// per-bucket: key = dst_local*4 + src_chunk (chunk-sorted edge lists for L2 locality)
__global__ void __launch_bounds__(512) k_bfinal(const int* __restrict__ pairs,
                                                const int* __restrict__ bbase,
                                                const int* __restrict__ gcur,
                                                int* __restrict__ rowstart,
                                                int* __restrict__ csr, int N) {
    __shared__ int h[2048];
    __shared__ int ts[512];
    __shared__ int loc[FCAP];
    int t = threadIdx.x;
    int b = blockIdx.x;
    int base = bbase[b];
    int cnt = gcur[b];
    const int* bp = pairs + (size_t)b * FSTRIDE;
    for (int i = t; i < 2048; i += 512) h[i] = 0;
    __syncthreads();
    for (int i = t; i < cnt; i += 512) {
        int p = bp[i];
        int key = ((p >> 18) << 2) | ((p & 0x3ffff) >> 16);
        atomicAdd(&h[key], 1);
    }
    __syncthreads();
    int v0 = h[4 * t], v1 = h[4 * t + 1], v2 = h[4 * t + 2], v3 = h[4 * t + 3];
    int lsum = v0 + v1 + v2 + v3;
    ts[t] = lsum; __syncthreads();
    for (int off = 1; off < 512; off <<= 1) {
        int u = (t >= off) ? ts[t - off] : 0; __syncthreads();
        ts[t] += u; __syncthreads();
    }
    int texcl = ts[t] - lsum;
    h[4 * t]     = texcl;
    h[4 * t + 1] = texcl + v0;
    h[4 * t + 2] = texcl + v0 + v1;
    h[4 * t + 3] = texcl + v0 + v1 + v2;
    int node = b * 512 + t;
    if (node < N) rowstart[node] = base + texcl;
    __syncthreads();
    bool fit = (cnt <= FCAP);
    for (int i = t; i < cnt; i += 512) {
        int p = bp[i];
        int key = ((p >> 18) << 2) | ((p & 0x3ffff) >> 16);
        int r = atomicAdd(&h[key], 1);
        int src = p & 0x3ffff;
        if (fit) loc[r] = src; else csr[base + r] = src;
    }
    __syncthreads();
    if (fit)
        for (int i = t; i < cnt; i += 512) csr[base + i] = loc[i];
}

// ---------------- degree-sorted node permutation (descending) ----------------
__global__ void __launch_bounds__(256) k_dhist(const int* __restrict__ rowstart,
                                               int* __restrict__ dh, int N) {
    __shared__ int h[512];
    int t = threadIdx.x;
    for (int i = t; i < 512; i += 256) h[i] = 0;
    __syncthreads();
    for (int i = blockIdx.x * 256 + t; i < N; i += gridDim.x * 256) {
        int d = min(rowstart[i + 1] - rowstart[i], 511);
        atomicAdd(&h[d], 1);
    }
    __syncthreads();
    for (int i = t; i < 512; i += 256)
        if (h[i]) atomicAdd(&dh[i], h[i]);
}

__global__ void __launch_bounds__(512) k_dscan(const int* __restrict__ dh,
                                               int* __restrict__ dcur) {
    __shared__ int s[512];
    int t = threadIdx.x;
    int v = dh[511 - t];
    s[t] = v; __syncthreads();
    for (int off = 1; off < 512; off <<= 1) {
        int u = (t >= off) ? s[t - off] : 0; __syncthreads();
        s[t] += u; __syncthreads();
    }
    dcur[511 - t] = s[t] - v;
}

__global__ void __launch_bounds__(256) k_dplace2(const int* __restrict__ rowstart,
                                                 int* __restrict__ dcur,
                                                 int* __restrict__ perm, int N) {
    __shared__ int h[512];
    __shared__ int base[512];
    int t = threadIdx.x;
    int c0 = blockIdx.x * DP_CH;
    int end = min(c0 + DP_CH, N);
    for (int i = t; i < 512; i += 256) h[i] = 0;
    __syncthreads();
    for (int i = c0 + t; i < end; i += 256) {
        int d = min(rowstart[i + 1] - rowstart[i], 511);
        atomicAdd(&h[d], 1);
    }
    __syncthreads();
    for (int i = t; i < 512; i += 256) {
        int c = h[i];
        base[i] = c ? atomicAdd(&dcur[i], c) : 0;
        h[i] = 0;
    }
    __syncthreads();
    for (int i = c0 + t; i < end; i += 256) {
        int d = min(rowstart[i + 1] - rowstart[i], 511);
        int r = atomicAdd(&h[d], 1);
        perm[base[d] + r] = i;
    }
}

// ---------------- weight pre-pack kernels ----------------
// layer1: w2p0 = packed fp16 pairs of g1w2
__global__ void k_prep0(const float* __restrict__ W2, unsigned* __restrict__ w2p) {
    int idx = blockIdx.x * 256 + threadIdx.x;
    if (idx < 512) {
        int k = idx >> 4, jj = idx & 15;
        w2p[idx] = packh2(W2[k * 32 + 2 * jj], W2[k * 32 + 2 * jj + 1]);
    }
}

// layers 2..5: fold BN affine into W1 (ROW scaling aa[k]!), pack fp16, cw32 = c@W1
__global__ void k_fin2(const float* __restrict__ pslot, const float* __restrict__ gam,
                       const float* __restrict__ bet, const float* __restrict__ W1,
                       const float* __restrict__ W2, int N,
                       unsigned* __restrict__ w1p, unsigned* __restrict__ w2p,
                       float* __restrict__ cw32) {
    __shared__ float aa[32], cc[32];
    int t = threadIdx.x;
    if (t < 32) {
        float s = 0.f, q = 0.f;
        #pragma unroll
        for (int r = 0; r < 8; r++) { s += pslot[r * 64 + t]; q += pslot[r * 64 + 32 + t]; }
        float mu = s / (float)N;
        float var = q / (float)N - mu * mu;
        float av = gam[t] * rsqrtf(var + BN_EPS);
        aa[t] = av;
        cc[t] = bet[t] - mu * av;
    }
    __syncthreads();
    for (int idx = t; idx < 512; idx += 256) {
        int k = idx >> 4, jj = idx & 15;
        // (diag(a) W1)[k][j] = a[k] * W1[k][j]  -- ROW scaling
        w1p[idx] = packh2(aa[k] * W1[k * 32 + 2 * jj],
                          aa[k] * W1[k * 32 + 2 * jj + 1]);
        w2p[idx] = packh2(W2[k * 32 + 2 * jj], W2[k * 32 + 2 * jj + 1]);
    }
    if (t < 32) {
        float acc = 0.f;
        for (int k = 0; k < 32; k++) acc += cc[k] * W1[k * 32 + t];
        cw32[t] = acc;
    }
}

// ---------------- GIN layers ----------------
// layer1 pre: Ub = fp16(x @ W1)  (78 -> 32)
__global__ void __launch_bounds__(256) k_A1(const float* __restrict__ x,
                                            const float* __restrict__ W,
                                            unsigned* __restrict__ Ub, int N) {
    __shared__ float xl[64 * 79];
    __shared__ float wl[78 * 33];
    int t = threadIdx.x;
    int n0 = blockIdx.x * 64;
    for (int idx = t; idx < 78 * 32; idx += 256)
        wl[(idx >> 5) * 33 + (idx & 31)] = W[idx];
    long base = (long)n0 * 78;
    for (int idx = t; idx < 64 * 78; idx += 256) {
        long g = base + idx;
        xl[(idx / 78) * 79 + (idx % 78)] = (g < (long)N * 78) ? x[g] : 0.f;
    }
    __syncthreads();
    int jp = t & 15, rg = t >> 4;
    for (int rep = 0; rep < 4; rep++) {
        int n = rg + 16 * rep;
        int node = n0 + n;
        if (node >= N) break;
        float a0 = 0.f, a1 = 0.f;
        #pragma unroll
        for (int k = 0; k < 78; k++) {
            float xv = xl[n * 79 + k];
            a0 += xv * wl[k * 33 + 2 * jp];
            a1 += xv * wl[k * 33 + 2 * jp + 1];
        }
        Ub[(size_t)node * 16 + jp] = packh2(a0, a1);
    }
}

// layer 1: 128 thr / 32 nodes; gather u-space; t=relu(s+b1); out=relu(t@W2p+b2)
__global__ void __launch_bounds__(128) k_BCS0(const uint4* __restrict__ Ub4,
                                              const int* __restrict__ rowstart,
                                              const int* __restrict__ csr,
                                              const int* __restrict__ perm,
                                              const float* __restrict__ b1,
                                              const unsigned* __restrict__ w2p,
                                              const float* __restrict__ b2,
                                              unsigned* __restrict__ Outb,
                                              float* __restrict__ slot, int N) {
    __shared__ float zl[32 * 33];
    __shared__ int nv[32];
    __shared__ float redS[4][33];
    __shared__ float redQ[4][33];
    int t = threadIdx.x;
    int g = t >> 2, l = t & 3;
    int gid = blockIdx.x * 32 + g;
    int node = (gid < N) ? perm[gid] : -1;
    if (l == 0) nv[g] = node;
    bool act = (node >= 0);
    int s0 = 0, s1 = 0;
    if (act) { s0 = rowstart[node]; s1 = rowstart[node + 1]; }
    float a[8] = {0.f, 0.f, 0.f, 0.f, 0.f, 0.f, 0.f, 0.f};
    if (act) addu4h(a, ldnt4(Ub4 + (size_t)node * 4 + l));
    int e = s0;
    for (; e + 3 < s1; e += 4) {
        int sa = csr[e], sb = csr[e + 1], sc = csr[e + 2], sd = csr[e + 3];
        uint4 va = ldnt4(Ub4 + (size_t)sa * 4 + l);
        uint4 vb = ldnt4(Ub4 + (size_t)sb * 4 + l);
        uint4 vc = ldnt4(Ub4 + (size_t)sc * 4 + l);
        uint4 vd = ldnt4(Ub4 + (size_t)sd * 4 + l);
        addu4h(a, va); addu4h(a, vb); addu4h(a, vc); addu4h(a, vd);
    }
    for (; e < s1; e++) addu4h(a, ldnt4(Ub4 + (size_t)csr[e] * 4 + l));
    int f0 = 8 * l;
    #pragma unroll
    for (int i = 0; i < 8; i++)
        zl[g * 33 + f0 + i] = fmaxf(a[i] + b1[f0 + i], 0.f);
    __syncthreads();

    // phase B: rows are 32-lane-group exclusive; in-wave LDS order -> in-place safe
    int j = t & 31, rg2 = t >> 5;
    float b2j = b2[j];
    float ps = 0.f, pq = 0.f;
    for (int rep = 0; rep < 8; rep++) {
        int n = rg2 + 4 * rep;
        float acc = b2j;
        #pragma unroll
        for (int k = 0; k < 32; k++) {
            unsigned wp = w2p[k * 16 + (j >> 1)];
            float wv = (j & 1) ? hi_h(wp) : lo_h(wp);
            acc += zl[n * 33 + k] * wv;
        }
        float xv = fmaxf(acc, 0.f);
        zl[n * 33 + j] = xv;
        if (nv[n] >= 0) { ps += xv; pq += xv * xv; }
    }
    redS[rg2][j] = ps; redQ[rg2][j] = pq;
    __syncthreads();
    if (t < 32) {
        float s = redS[0][t] + redS[1][t] + redS[2][t] + redS[3][t];
        float q = redQ[0][t] + redQ[1][t] + redQ[2][t] + redQ[3][t];
        int rep2 = blockIdx.x & 7;
        atomicAdd(&slot[rep2 * 64 + t], s);
        atomicAdd(&slot[rep2 * 64 + 32 + t], q);
    }
    for (int idx = t; idx < 512; idx += 128) {
        int n = idx >> 4, jp = idx & 15;
        int nod = nv[n];
        if (nod >= 0)
            Outb[(size_t)nod * 16 + jp] = packh2(zl[n * 33 + 2 * jp], zl[n * 33 + 2 * jp + 1]);
    }
}

// layers 2..5: 128 thr / 32 nodes; gather fp16 rows; BN folded via packed w1p + cw32
__global__ void __launch_bounds__(128) k_BCS1(const uint4* __restrict__ Xb4,
                                              const int* __restrict__ rowstart,
                                              const int* __restrict__ csr,
                                              const int* __restrict__ perm,
                                              const unsigned* __restrict__ w1p,
                                              const unsigned* __restrict__ w2p,
                                              const float* __restrict__ cw32,
                                              const float* __restrict__ b1,
                                              const float* __restrict__ b2,
                                              unsigned* __restrict__ Outb,
                                              float* __restrict__ slot, int N) {
    __shared__ float zl[32 * 33];
    __shared__ float dp1[32];
    __shared__ int nv[32];
    __shared__ float redS[4][33];
    __shared__ float redQ[4][33];
    int t = threadIdx.x;
    int g = t >> 2, l = t & 3;
    int gid = blockIdx.x * 32 + g;
    int node = (gid < N) ? perm[gid] : -1;
    bool act = (node >= 0);
    int s0 = 0, s1 = 0;
    if (act) { s0 = rowstart[node]; s1 = rowstart[node + 1]; }
    if (l == 0) { nv[g] = node; dp1[g] = (float)(s1 - s0 + 1); }
    float a[8] = {0.f, 0.f, 0.f, 0.f, 0.f, 0.f, 0.f, 0.f};
    if (act) addu4h(a, ldnt4(Xb4 + (size_t)node * 4 + l));
    int e = s0;
    for (; e + 3 < s1; e += 4) {
        int sa = csr[e], sb = csr[e + 1], sc = csr[e + 2], sd = csr[e + 3];
        uint4 va = ldnt4(Xb4 + (size_t)sa * 4 + l);
        uint4 vb = ldnt4(Xb4 + (size_t)sb * 4 + l);
        uint4 vc = ldnt4(Xb4 + (size_t)sc * 4 + l);
        uint4 vd = ldnt4(Xb4 + (size_t)sd * 4 + l);
        addu4h(a, va); addu4h(a, vb); addu4h(a, vc); addu4h(a, vd);
    }
    for (; e < s1; e++) addu4h(a, ldnt4(Xb4 + (size_t)csr[e] * 4 + l));
    int f0 = 8 * l;
    #pragma unroll
    for (int i = 0; i < 8; i++) zl[g * 33 + f0 + i] = a[i];
    __syncthreads();

    // phase B: z-row -> t-row -> out-row in place (group-exclusive rows)
    int j = t & 31, rg2 = t >> 5;
    float cwj = cw32[j], b1j = b1[j], b2j = b2[j];
    float ps = 0.f, pq = 0.f;
    for (int rep = 0; rep < 8; rep++) {
        int n = rg2 + 4 * rep;
        float acc = dp1[n] * cwj + b1j;
        #pragma unroll
        for (int k = 0; k < 32; k++) {
            unsigned wp = w1p[k * 16 + (j >> 1)];
            float wv = (j & 1) ? hi_h(wp) : lo_h(wp);
            acc += zl[n * 33 + k] * wv;
        }
        zl[n * 33 + j] = fmaxf(acc, 0.f);
        float o = b2j;
        #pragma unroll
        for (int k = 0; k < 32; k++) {
            unsigned wp = w2p[k * 16 + (j >> 1)];
            float wv = (j & 1) ? hi_h(wp) : lo_h(wp);
            o += zl[n * 33 + k] * wv;
        }
        float xv = fmaxf(o, 0.f);
        zl[n * 33 + j] = xv;
        if (nv[n] >= 0) { ps += xv; pq += xv * xv; }
    }
    redS[rg2][j] = ps; redQ[rg2][j] = pq;
    __syncthreads();
    if (t < 32) {
        float s = redS[0][t] + redS[1][t] + redS[2][t] + redS[3][t];
        float q = redQ[0][t] + redQ[1][t] + redQ[2][t] + redQ[3][t];
        int rep2 = blockIdx.x & 7;
        atomicAdd(&slot[rep2 * 64 + t], s);
        atomicAdd(&slot[rep2 * 64 + 32 + t], q);
    }
    for (int idx = t; idx < 512; idx += 128) {
        int n = idx >> 4, jp = idx & 15;
        int nod = nv[n];
        if (nod >= 0)
            Outb[(size_t)nod * 16 + jp] = packh2(zl[n * 33 + 2 * jp], zl[n * 33 + 2 * jp + 1]);
    }
}

// pool h5 = out5*a+c per graph from fp16 out5, then xd = relu(pooled@fcxd_w+b)
__global__ void __launch_bounds__(128) k_pool(const unsigned short* __restrict__ Xb,
                                              const int* __restrict__ batch,
                                              const float* __restrict__ pslot,
                                              const float* __restrict__ pgam,
                                              const float* __restrict__ pbet,
                                              const float* __restrict__ fw,
                                              const float* __restrict__ fb,
                                              float* __restrict__ xc, int N) {
    __shared__ float red[4][32];
    __shared__ float pv[32];
    __shared__ float aa[32], cc[32];
    int g = blockIdx.x, t = threadIdx.x;
    if (t < 32) {
        float s = 0.f, q = 0.f;
        #pragma unroll
        for (int r = 0; r < 8; r++) { s += pslot[r * 64 + t]; q += pslot[r * 64 + 32 + t]; }
        float mu = s / (float)N;
        float var = q / (float)N - mu * mu;
        float av = pgam[t] * rsqrtf(var + BN_EPS);
        aa[t] = av;
        cc[t] = pbet[t] - mu * av;
    }
    int lo = lbound(batch, N, g);
    int hi = lbound(batch, N, g + 1);
    int j = t & 31, rs = t >> 5;
    float ps = 0.f;
    for (int i = lo + rs; i < hi; i += 4) ps += h2f(Xb[(size_t)i * 32 + j]);
    red[rs][j] = ps; __syncthreads();
    if (t < 32) {
        float s = red[0][t] + red[1][t] + red[2][t] + red[3][t];
        pv[t] = s * aa[t] + (float)(hi - lo) * cc[t];
    }
    __syncthreads();
    float acc = fb[t];
    for (int k = 0; k < 32; k++) acc += pv[k] * fw[k * 128 + t];
    xc[g * 256 + t] = fmaxf(acc, 0.f);
}

// ---------------- protein branch ----------------
__global__ void __launch_bounds__(128) k_F2(const float* __restrict__ Emb,
                                            const float* __restrict__ fcxt,
                                            float* __restrict__ F) {
    __shared__ float er[128];
    int bid = blockIdx.x;
    int v = bid >> 5, o = bid & 31;
    int t = threadIdx.x;
    er[t] = Emb[v * 128 + t];
    __syncthreads();
    float acc[8] = {0.f, 0.f, 0.f, 0.f, 0.f, 0.f, 0.f, 0.f};
    for (int p = 0; p < 121; p++) {
        float fv = fcxt[(o * 121 + p) * 128 + t];
        #pragma unroll
        for (int k = 0; k < 8; k++) acc[k] += er[p + k] * fv;
    }
    #pragma unroll
    for (int k = 0; k < 8; k++)
        F[((size_t)v * 256 + o * 8 + k) * 128 + t] = acc[k];
}

__global__ void __launch_bounds__(128) k_cb(const float* __restrict__ fcxt,
                                            const float* __restrict__ fb,
                                            const float* __restrict__ cb,
                                            float* __restrict__ cbias) {
    int o = blockIdx.x, t = threadIdx.x;
    float acc = 0.f;
    for (int p = 0; p < 121; p++) acc += fcxt[(o * 121 + p) * 128 + t];
    float val = cb[o] * acc;
    if (o == 0) val += fb[t];
    atomicAdd(&cbias[t], val);
}

// Dm_h[c][v][j] = fp16( sum_ok cw[o][c][kk] * F[v][ok][j] ); c-tile 32 (832 blocks)
__global__ void __launch_bounds__(256) k_D2(const float* __restrict__ cw,
                                            const float* __restrict__ F,
                                            unsigned* __restrict__ Dmb) {
    __shared__ float Fl[32][128];
    __shared__ float Wl[32][33];
    int v = blockIdx.y;
    int c0 = blockIdx.x * 32;
    int t = threadIdx.x;
    int jg = t & 31, j0 = jg * 4;
    int cg = t >> 5;                 // 0..7, 4 c each
    float4 acc[4];
    #pragma unroll
    for (int i = 0; i < 4; i++) acc[i] = make_float4(0.f, 0.f, 0.f, 0.f);
    for (int chunk = 0; chunk < 8; chunk++) {
        int k0 = chunk * 32;
        __syncthreads();
        for (int idx = t; idx < 4096; idx += 256) {
            int k = idx >> 7, j = idx & 127;
            Fl[k][j] = F[((size_t)v * 256 + k0 + k) * 128 + j];
        }
        for (int idx = t; idx < 1024; idx += 256) {
            int k = idx >> 5, c = idx & 31;
            int ok = k0 + k;
            Wl[k][c] = (c0 + c < 1000) ? cw[((ok >> 3) * 1000 + c0 + c) * 8 + (ok & 7)] : 0.f;
        }
        __syncthreads();
        for (int k = 0; k < 32; k++) {
            float4 fv = *(const float4*)&Fl[k][j0];
            #pragma unroll
            for (int ci = 0; ci < 4; ci++) {
                float wv = Wl[k][cg * 4 + ci];
                acc[ci].x += wv * fv.x;
                acc[ci].y += wv * fv.y;
                acc[ci].z += wv * fv.z;
                acc[ci].w += wv * fv.w;
            }
        }
    }
    #pragma unroll
    for (int ci = 0; ci < 4; ci++) {
        int c = c0 + cg * 4 + ci;
        if (c < 1000) {
            uint2 pk;
            pk.x = packh2(acc[ci].x, acc[ci].y);
            pk.y = packh2(acc[ci].z, acc[ci].w);
            *(uint2*)&Dmb[((size_t)c * 26 + v) * 64 + jg * 2] = pk;
        }
    }
}

// xt: one block per graph; 16 c-lanes x 16 j-lanes; no atomics
__global__ void __launch_bounds__(256) k_xt3(const int* __restrict__ target,
                                             const uint4* __restrict__ Dm4,
                                             const float* __restrict__ cbias,
                                             float* __restrict__ xc) {
    __shared__ int tl[1000];
    __shared__ float red[16][132];
    int b = blockIdx.x, t = threadIdx.x;
    for (int i = t; i < 1000; i += 256) tl[i] = target[(size_t)b * 1000 + i];
    __syncthreads();
    int cl = t >> 4;
    int jg = t & 15;
    float acc[8] = {0.f, 0.f, 0.f, 0.f, 0.f, 0.f, 0.f, 0.f};
    for (int c = cl; c < 1000; c += 16) {
        int v = tl[c];
        uint4 d = Dm4[((size_t)c * 26 + v) * 16 + jg];
        acc[0] += lo_h(d.x); acc[1] += hi_h(d.x);
        acc[2] += lo_h(d.y); acc[3] += hi_h(d.y);
        acc[4] += lo_h(d.z); acc[5] += hi_h(d.z);
        acc[6] += lo_h(d.w); acc[7] += hi_h(d.w);
    }
    #pragma unroll
    for (int fi = 0; fi < 8; fi++) red[cl][jg * 8 + fi] = acc[fi];
    __syncthreads();
    if (t < 128) {
        float s = 0.f;
        #pragma unroll
        for (int r = 0; r < 16; r++) s += red[r][t];
        xc[(size_t)b * 256 + 128 + t] = cbias[t] + s;
    }
}

// ---------------- head ----------------
__global__ void __launch_bounds__(256) k_fc1(const float* __restrict__ xc,
                                             const float* __restrict__ w,
                                             const float* __restrict__ bias,
                                             float* __restrict__ y1) {
    __shared__ float xl[16 * 256];
    int t = threadIdx.x;
    int q0 = blockIdx.x * 256, b0 = blockIdx.y * 16;
    for (int idx = t; idx < 4096; idx += 256) xl[idx] = xc[b0 * 256 + idx];
    __syncthreads();
    int ql = t & 63, q = q0 + ql * 4;
    int bg = t >> 6;
    float4 bv = *(const float4*)&bias[q];
    float4 acc0 = bv, acc1 = bv, acc2 = bv, acc3 = bv;
    const float* xr = &xl[bg * 4 * 256];
    #pragma unroll 4
    for (int k = 0; k < 256; k++) {
        float4 wv = *(const float4*)&w[k * 1024 + q];
        float x0 = xr[k], x1 = xr[256 + k], x2 = xr[512 + k], x3 = xr[768 + k];
        acc0.x += x0 * wv.x; acc0.y += x0 * wv.y; acc0.z += x0 * wv.z; acc0.w += x0 * wv.w;
        acc1.x += x1 * wv.x; acc1.y += x1 * wv.y; acc1.z += x1 * wv.z; acc1.w += x1 * wv.w;
        acc2.x += x2 * wv.x; acc2.y += x2 * wv.y; acc2.z += x2 * wv.z; acc2.w += x2 * wv.w;
        acc3.x += x3 * wv.x; acc3.y += x3 * wv.y; acc3.z += x3 * wv.z; acc3.w += x3 * wv.w;
    }
    int b = b0 + bg * 4;
    float4 r;
    r.x = fmaxf(acc0.x, 0.f); r.y = fmaxf(acc0.y, 0.f); r.z = fmaxf(acc0.z, 0.f); r.w = fmaxf(acc0.w, 0.f);
    *(float4*)&y1[(size_t)b * 1024 + q] = r;
    r.x = fmaxf(acc1.x, 0.f); r.y = fmaxf(acc1.y, 0.f); r.z = fmaxf(acc1.z, 0.f); r.w = fmaxf(acc1.w, 0.f);
    *(float4*)&y1[(size_t)(b + 1) * 1024 + q] = r;
    r.x = fmaxf(acc2.x, 0.f); r.y = fmaxf(acc2.y, 0.f); r.z = fmaxf(acc2.z, 0.f); r.w = fmaxf(acc2.w, 0.f);
    *(float4*)&y1[(size_t)(b + 2) * 1024 + q] = r;
    r.x = fmaxf(acc3.x, 0.f); r.y = fmaxf(acc3.y, 0.f); r.z = fmaxf(acc3.z, 0.f); r.w = fmaxf(acc3.w, 0.f);
    *(float4*)&y1[(size_t)(b + 3) * 1024 + q] = r;
}

__global__ void k_wcomb(const float* __restrict__ fc2w, const float* __restrict__ fc2b,
                        const float* __restrict__ ow, const float* __restrict__ ob,
                        float* __restrict__ wc) {
    int p = blockIdx.x * 256 + threadIdx.x;
    float acc = 0.f;
    for (int q = 0; q < 256; q++) acc += fc2w[p * 256 + q] * ow[q];
    wc[p] = acc;
    if (p == 0) {
        float bc = ob[0];
        for (int q = 0; q < 256; q++) bc += fc2b[q] * ow[q];
        wc[1024] = bc;
    }
}

__global__ void __launch_bounds__(256) k_out(const float* __restrict__ y1,
                                             const float* __restrict__ wc,
                                             float* __restrict__ out) {
    __shared__ float r[256];
    int b = blockIdx.x, t = threadIdx.x;
    float acc = 0.f;
    for (int p = t; p < 1024; p += 256) acc += y1[b * 1024 + p] * wc[p];
    r[t] = acc; __syncthreads();
    for (int off = 128; off > 0; off >>= 1) {
        if (t < off) r[t] += r[t + off];
        __syncthreads();
    }
    if (t == 0) out[b] = r[0] + wc[1024];
}

extern "C" void kernel_launch(void* const* d_in, const int* in_sizes, int n_in,
                              void* d_out, int out_size, void* d_ws, size_t ws_size,
                              hipStream_t stream) {
    const float* x     = (const float*)d_in[0];
    const int*   ei    = (const int*)d_in[1];
    const int*   batch = (const int*)d_in[2];
    const int*   targ  = (const int*)d_in[3];
    const float* g1w1  = (const float*)d_in[4];
    const float* g1b1  = (const float*)d_in[5];
    const float* g1w2  = (const float*)d_in[6];
    const float* g1b2  = (const float*)d_in[7];
    const float* gW1   = (const float*)d_in[8];
    const float* gb1   = (const float*)d_in[9];
    const float* gW2   = (const float*)d_in[10];
    const float* gb2   = (const float*)d_in[11];
    const float* gam   = (const float*)d_in[12];
    const float* bet   = (const float*)d_in[13];
    const float* fcxdw = (const float*)d_in[14];
    const float* fcxdb = (const float*)d_in[15];
    const float* emb   = (const float*)d_in[16];
    const float* convw = (const float*)d_in[17];
    const float* convb = (const float*)d_in[18];
    const float* fcxtw = (const float*)d_in[19];
    const float* fcxtb = (const float*)d_in[20];
    const float* fc1w  = (const float*)d_in[21];
    const float* fc1b  = (const float*)d_in[22];
    const float* fc2w  = (const float*)d_in[23];
    const float* fc2b  = (const float*)d_in[24];
    const float* outw  = (const float*)d_in[25];
    const float* outb  = (const float*)d_in[26];

    int N = in_sizes[2];
    int E = in_sizes[1] / 2;
    int B = in_sizes[3] / 1000;
    int NB = (N + 511) >> BSHIFT;

    char* ws = (char*)d_ws;
    size_t off = 0;
    auto alloc = [&](size_t bytes) -> void* {
        void* p = ws + off;
        off += (bytes + 255) & ~(size_t)255;
        return p;
    };
    int*   rowstart = (int*)alloc((size_t)(N + 1) * 4);
    int*   bbase    = (int*)alloc((NBMAX + 1) * 4);
    int*   gcur     = (int*)alloc(NBMAX * 4);
    int*   csr      = (int*)alloc((size_t)E * 4);
    int*   perm     = (int*)alloc((size_t)N * 4);
    int*   dh       = (int*)alloc(512 * 4);
    int*   dcur     = (int*)alloc(512 * 4);
    // packed weight tables
    unsigned* w2p0  = (unsigned*)alloc(512 * 4);
    unsigned* w1pA  = (unsigned*)alloc(4 * 512 * 4);
    unsigned* w2pA  = (unsigned*)alloc(4 * 512 * 4);
    float*    cwA   = (float*)alloc(4 * 32 * 4);
    // Xb double buffer (2 x N*64B); pairs (NB*FSTRIDE*4) aliases it (dead before first Xb write)
    size_t xb_bytes = (size_t)N * 64;
    size_t pairs_bytes = (size_t)NB * FSTRIDE * 4;
    char*  blk      = (char*)alloc(2 * xb_bytes > pairs_bytes ? 2 * xb_bytes : pairs_bytes);
    unsigned* XbA   = (unsigned*)blk;
    unsigned* XbB   = (unsigned*)(blk + xb_bytes);
    int*   pairs    = (int*)blk;
    unsigned* Ub    = (unsigned*)alloc((size_t)N * 16 * 4);
    float* stats    = (float*)alloc((size_t)5 * 640 * 4);
    float* xc       = (float*)alloc((size_t)B * 256 * 4);
    float* Fb       = (float*)alloc((size_t)26 * 256 * 128 * 4);
    unsigned* Dmb   = (unsigned*)alloc((size_t)1000 * 26 * 64 * 4);
    float* cbias    = (float*)alloc(128 * 4);
    float* y1       = (float*)alloc((size_t)B * 1024 * 4);
    float* wc       = (float*)alloc(1025 * 4);

    hipMemsetAsync(gcur, 0, NBMAX * 4, stream);
    hipMemsetAsync(dh, 0, 512 * 4, stream);
    hipMemsetAsync(stats, 0, (size_t)5 * 640 * 4, stream);
    hipMemsetAsync(cbias, 0, 128 * 4, stream);

    // CSR build (chunk-sorted edge lists for L2-resident gathers)
    k_bscatter<<<(E + SCAT_CH - 1) / SCAT_CH, 256, 0, stream>>>(ei, gcur, pairs, E, NB);
    k_bscan<<<1, 512, 0, stream>>>(gcur, bbase, rowstart, N, E, NB);
    k_bfinal<<<NB, 512, 0, stream>>>(pairs, bbase, gcur, rowstart, csr, N);

    // degree-sorted node permutation (descending); two-level placement
    k_dhist<<<256, 256, 0, stream>>>(rowstart, dh, N);
    k_dscan<<<1, 512, 0, stream>>>(dh, dcur);
    k_dplace2<<<(N + DP_CH - 1) / DP_CH, 256, 0, stream>>>(rowstart, dcur, perm, N);

    int gBCS = (N + 31) / 32;

    // layer 1: out1 -> XbA, stats slot0
    k_prep0<<<2, 256, 0, stream>>>(g1w2, w2p0);
    k_A1<<<(N + 63) / 64, 256, 0, stream>>>(x, g1w1, Ub, N);
    k_BCS0<<<gBCS, 128, 0, stream>>>((const uint4*)Ub, rowstart, csr, perm,
                                     g1b1, w2p0, g1b2, XbA, stats, N);

    // layers 2..5
    unsigned* bufs[2] = {XbA, XbB};
    for (int i = 0; i < 4; i++) {
        unsigned* src = bufs[i & 1];
        unsigned* dst = bufs[(i + 1) & 1];
        k_fin2<<<1, 256, 0, stream>>>(stats + (size_t)i * 640, gam + i * 32, bet + i * 32,
                                      gW1 + i * 1024, gW2 + i * 1024, N,
                                      w1pA + i * 512, w2pA + i * 512, cwA + i * 32);
        k_BCS1<<<gBCS, 128, 0, stream>>>((const uint4*)src, rowstart, csr, perm,
                                         w1pA + i * 512, w2pA + i * 512, cwA + i * 32,
                                         gb1 + i * 32, gb2 + i * 32,
                                         dst, stats + (size_t)(i + 1) * 640, N);
    }
    // out5 ended in bufs[0] (XbA)

    // pooling + xd -> xc[:, 0:128]
    k_pool<<<B, 128, 0, stream>>>((const unsigned short*)XbA, batch,
                                  stats + (size_t)4 * 640, gam + 128, bet + 128,
                                  fcxdw, fcxdb, xc, N);

    // protein branch -> xc[:, 128:256]
    k_F2<<<26 * 32, 128, 0, stream>>>(emb, fcxtw, Fb);
    k_cb<<<32, 128, 0, stream>>>(fcxtw, fcxtb, convb, cbias);
    dim3 gD(32, 26);
    k_D2<<<gD, 256, 0, stream>>>(convw, Fb, Dmb);
    k_xt3<<<B, 256, 0, stream>>>(targ, (const uint4*)Dmb, cbias, xc);

    // head
    dim3 g1(4, B / 16);
    k_fc1<<<g1, 256, 0, stream>>>(xc, fc1w, fc1b, y1);
    k_wcomb<<<4, 256, 0, stream>>>(fc2w, fc2b, outw, outb, wc);
    k_out<<<B, 256, 0, stream>>>(y1, wc, (float*)d_out);
}

// Round 13
// 653.427 us; speedup vs baseline: 1.1339x; 1.1339x over previous
//
#include <hip/hip_runtime.h>
#include <hip/hip_fp16.h>

#define HID 32
#define BN_EPS 1e-5f
#define NBMAX 512
#define BSHIFT 9
#define SCAT_CH 8192
#define FSTRIDE 10240
#define FCAP 10240
#define DP_CH 4096

static __device__ __forceinline__ int lbound(const int* a, int n, int key) {
    int lo = 0, hi = n;
    while (lo < hi) { int m = (lo + hi) >> 1; if (a[m] < key) lo = m + 1; else hi = m; }
    return lo;
}

static __device__ __forceinline__ unsigned packh2(float a, float b) {
    __half2 h = __floats2half2_rn(a, b);
    return *reinterpret_cast<unsigned*>(&h);
}
static __device__ __forceinline__ float lo_h(unsigned v) {
    __half2 h = *reinterpret_cast<__half2*>(&v);
    return __low2float(h);
}
static __device__ __forceinline__ float hi_h(unsigned v) {
    __half2 h = *reinterpret_cast<__half2*>(&v);
    return __high2float(h);
}
static __device__ __forceinline__ float h2f(unsigned short v) {
    return __half2float(__ushort_as_half(v));
}

static __device__ __forceinline__ void addu4h(float* a, uint4 v) {
    a[0] += lo_h(v.x); a[1] += hi_h(v.x);
    a[2] += lo_h(v.y); a[3] += hi_h(v.y);
    a[4] += lo_h(v.z); a[5] += hi_h(v.z);
    a[6] += lo_h(v.w); a[7] += hi_h(v.w);
}

// ---------------- bucketed CSR build ----------------
__global__ void __launch_bounds__(256) k_bscatter(const int* __restrict__ ei,
                                                  int* __restrict__ gcur,
                                                  int* __restrict__ pairs, int E, int NB) {
    __shared__ int h[NBMAX];
    __shared__ int lb[NBMAX];
    int t = threadIdx.x;
    int c0 = blockIdx.x * SCAT_CH;
    int end = min(c0 + SCAT_CH, E);
    for (int i = t; i < NBMAX; i += 256) h[i] = 0;
    __syncthreads();
    for (int i = c0 + t; i < end; i += 256)
        atomicAdd(&h[ei[E + i] >> BSHIFT], 1);
    __syncthreads();
    for (int b = t; b < NB; b += 256) {
        int c = h[b];
        lb[b] = c ? atomicAdd(&gcur[b], c) : 0;
        h[b] = 0;
    }
    __syncthreads();
    for (int i = c0 + t; i < end; i += 256) {
        int src = ei[i], d = ei[E + i];
        int bkt = d >> BSHIFT;
        int r = atomicAdd(&h[bkt], 1);
        pairs[bkt * FSTRIDE + lb[bkt] + r] = src | ((d & 511) << 18);
    }
}

__global__ void __launch_bounds__(512) k_bscan(const int* __restrict__ gcur,
                                               int* __restrict__ bbase,
                                               int* __restrict__ rowstart,
                                               int N, int E, int NB) {
    __shared__ int s[512];
    int t = threadIdx.x;
    int v = (t < NB) ? gcur[t] : 0;
    s[t] = v; __syncthreads();
    for (int off = 1; off < 512; off <<= 1) {
        int u = (t >= off) ? s[t - off] : 0; __syncthreads();
        s[t] += u; __syncthreads();
    }
    int excl = s[t] - v;
    if (t < NB) bbase[t] = excl;
    if (t == NB - 1) bbase[NB] = s[t];
    if (t == 0) rowstart[N] = E;
}

// per-bucket: key = dst_local*4 + src_chunk (chunk-sorted edge lists for L2 locality)
__global__ void __launch_bounds__(512) k_bfinal(const int* __restrict__ pairs,
                                                const int* __restrict__ bbase,
                                                const int* __restrict__ gcur,
                                                int* __restrict__ rowstart,
                                                int* __restrict__ csr, int N) {
    __shared__ int h[2048];
    __shared__ int ts[512];
    __shared__ int loc[FCAP];
    int t = threadIdx.x;
    int b = blockIdx.x;
    int base = bbase[b];
    int cnt = gcur[b];
    const int* bp = pairs + (size_t)b * FSTRIDE;
    for (int i = t; i < 2048; i += 512) h[i] = 0;
    __syncthreads();
    for (int i = t; i < cnt; i += 512) {
        int p = bp[i];
        int key = ((p >> 18) << 2) | ((p & 0x3ffff) >> 16);
        atomicAdd(&h[key], 1);
    }
    __syncthreads();
    int v0 = h[4 * t], v1 = h[4 * t + 1], v2 = h[4 * t + 2], v3 = h[4 * t + 3];
    int lsum = v0 + v1 + v2 + v3;
    ts[t] = lsum; __syncthreads();
    for (int off = 1; off < 512; off <<= 1) {
        int u = (t >= off) ? ts[t - off] : 0; __syncthreads();
        ts[t] += u; __syncthreads();
    }
    int texcl = ts[t] - lsum;
    h[4 * t]     = texcl;
    h[4 * t + 1] = texcl + v0;
    h[4 * t + 2] = texcl + v0 + v1;
    h[4 * t + 3] = texcl + v0 + v1 + v2;
    int node = b * 512 + t;
    if (node < N) rowstart[node] = base + texcl;
    __syncthreads();
    bool fit = (cnt <= FCAP);
    for (int i = t; i < cnt; i += 512) {
        int p = bp[i];
        int key = ((p >> 18) << 2) | ((p & 0x3ffff) >> 16);
        int r = atomicAdd(&h[key], 1);
        int src = p & 0x3ffff;
        if (fit) loc[r] = src; else csr[base + r] = src;
    }
    __syncthreads();
    if (fit)
        for (int i = t; i < cnt; i += 512) csr[base + i] = loc[i];
}

// ---------------- degree-sorted node permutation (descending) ----------------
__global__ void __launch_bounds__(256) k_dhist(const int* __restrict__ rowstart,
                                               int* __restrict__ dh, int N) {
    __shared__ int h[512];
    int t = threadIdx.x;
    for (int i = t; i < 512; i += 256) h[i] = 0;
    __syncthreads();
    for (int i = blockIdx.x * 256 + t; i < N; i += gridDim.x * 256) {
        int d = min(rowstart[i + 1] - rowstart[i], 511);
        atomicAdd(&h[d], 1);
    }
    __syncthreads();
    for (int i = t; i < 512; i += 256)
        if (h[i]) atomicAdd(&dh[i], h[i]);
}

__global__ void __launch_bounds__(512) k_dscan(const int* __restrict__ dh,
                                               int* __restrict__ dcur) {
    __shared__ int s[512];
    int t = threadIdx.x;
    int v = dh[511 - t];
    s[t] = v; __syncthreads();
    for (int off = 1; off < 512; off <<= 1) {
        int u = (t >= off) ? s[t - off] : 0; __syncthreads();
        s[t] += u; __syncthreads();
    }
    dcur[511 - t] = s[t] - v;
}

__global__ void __launch_bounds__(256) k_dplace2(const int* __restrict__ rowstart,
                                                 int* __restrict__ dcur,
                                                 int* __restrict__ perm, int N) {
    __shared__ int h[512];
    __shared__ int base[512];
    int t = threadIdx.x;
    int c0 = blockIdx.x * DP_CH;
    int end = min(c0 + DP_CH, N);
    for (int i = t; i < 512; i += 256) h[i] = 0;
    __syncthreads();
    for (int i = c0 + t; i < end; i += 256) {
        int d = min(rowstart[i + 1] - rowstart[i], 511);
        atomicAdd(&h[d], 1);
    }
    __syncthreads();
    for (int i = t; i < 512; i += 256) {
        int c = h[i];
        base[i] = c ? atomicAdd(&dcur[i], c) : 0;
        h[i] = 0;
    }
    __syncthreads();
    for (int i = c0 + t; i < end; i += 256) {
        int d = min(rowstart[i + 1] - rowstart[i], 511);
        int r = atomicAdd(&h[d], 1);
        perm[base[d] + r] = i;
    }
}

// ---------------- GIN layers ----------------
// layer1 pre: Ub = fp16(x @ W1)  (78 -> 32)
__global__ void __launch_bounds__(256) k_A1(const float* __restrict__ x,
                                            const float* __restrict__ W,
                                            unsigned* __restrict__ Ub, int N) {
    __shared__ float xl[64 * 79];
    __shared__ float wl[78 * 33];
    int t = threadIdx.x;
    int n0 = blockIdx.x * 64;
    for (int idx = t; idx < 78 * 32; idx += 256)
        wl[(idx >> 5) * 33 + (idx & 31)] = W[idx];
    long base = (long)n0 * 78;
    for (int idx = t; idx < 64 * 78; idx += 256) {
        long g = base + idx;
        xl[(idx / 78) * 79 + (idx % 78)] = (g < (long)N * 78) ? x[g] : 0.f;
    }
    __syncthreads();
    int jp = t & 15, rg = t >> 4;
    for (int rep = 0; rep < 4; rep++) {
        int n = rg + 16 * rep;
        int node = n0 + n;
        if (node >= N) break;
        float a0 = 0.f, a1 = 0.f;
        #pragma unroll
        for (int k = 0; k < 78; k++) {
            float xv = xl[n * 79 + k];
            a0 += xv * wl[k * 33 + 2 * jp];
            a1 += xv * wl[k * 33 + 2 * jp + 1];
        }
        Ub[(size_t)node * 16 + jp] = packh2(a0, a1);
    }
}

// layer 1: degree-sorted nodes; gather u-space; t=relu(s+b1); out=relu(t@W2+b2) in-place
__global__ void __launch_bounds__(256) k_BCS0(const uint4* __restrict__ Ub4,
                                              const int* __restrict__ rowstart,
                                              const int* __restrict__ csr,
                                              const int* __restrict__ perm,
                                              const float* __restrict__ b1,
                                              const float* __restrict__ W2,
                                              const float* __restrict__ b2,
                                              unsigned* __restrict__ Outb,
                                              float* __restrict__ slot, int N) {
    __shared__ float w2s[32 * 33];
    __shared__ float tl[64 * 33];
    __shared__ float redS[8][33];
    __shared__ float redQ[8][33];
    __shared__ int pl[64];
    int t = threadIdx.x;
    for (int idx = t; idx < 1024; idx += 256)
        w2s[(idx >> 5) * 33 + (idx & 31)] = W2[idx];
    if (t < 64) {
        int gid = blockIdx.x * 64 + t;
        pl[t] = (gid < N) ? perm[gid] : -1;
    }
    __syncthreads();

    int g = t >> 2, l = t & 3;
    int node = pl[g];
    bool act = (node >= 0);
    int s0 = 0, s1 = 0;
    if (act) { s0 = rowstart[node]; s1 = rowstart[node + 1]; }
    float a[8] = {0.f, 0.f, 0.f, 0.f, 0.f, 0.f, 0.f, 0.f};
    if (act) addu4h(a, Ub4[(size_t)node * 4 + l]);
    int e = s0;
    for (; e + 3 < s1; e += 4) {
        int sa = csr[e], sb = csr[e + 1], sc = csr[e + 2], sd = csr[e + 3];
        uint4 va = Ub4[(size_t)sa * 4 + l];
        uint4 vb = Ub4[(size_t)sb * 4 + l];
        uint4 vc = Ub4[(size_t)sc * 4 + l];
        uint4 vd = Ub4[(size_t)sd * 4 + l];
        addu4h(a, va); addu4h(a, vb); addu4h(a, vc); addu4h(a, vd);
    }
    for (; e < s1; e++) addu4h(a, Ub4[(size_t)csr[e] * 4 + l]);
    int f0 = 8 * l;
    #pragma unroll
    for (int i = 0; i < 8; i++)
        tl[g * 33 + f0 + i] = fmaxf(a[i] + b1[f0 + i], 0.f);
    __syncthreads();

    // phase B: rows half-wave-exclusive; in-wave LDS in-order -> in-place safe
    int j = t & 31, rg2 = t >> 5;
    float ps = 0.f, pq = 0.f;
    for (int rep = 0; rep < 8; rep++) {
        int n = rg2 + 8 * rep;
        float acc = b2[j];
        #pragma unroll
        for (int k = 0; k < 32; k++) acc += tl[n * 33 + k] * w2s[k * 33 + j];
        float xv = fmaxf(acc, 0.f);
        tl[n * 33 + j] = xv;
        if (pl[n] >= 0) { ps += xv; pq += xv * xv; }
    }
    redS[rg2][j] = ps; redQ[rg2][j] = pq;
    __syncthreads();
    if (t < 32) {
        float s = 0.f, q = 0.f;
        #pragma unroll
        for (int r = 0; r < 8; r++) { s += redS[r][t]; q += redQ[r][t]; }
        int rep = blockIdx.x & 7;
        atomicAdd(&slot[rep * 64 + t], s);
        atomicAdd(&slot[rep * 64 + 32 + t], q);
    }
    for (int idx = t; idx < 1024; idx += 256) {
        int n = idx >> 4, jp = idx & 15;
        int nod = pl[n];
        if (nod >= 0)
            Outb[(size_t)nod * 16 + jp] = packh2(tl[n * 33 + 2 * jp], tl[n * 33 + 2 * jp + 1]);
    }
}

// layers 2..5: degree-sorted; gather fp16 out rows; BN+W1 folded; both GEMMs in-place
__global__ void __launch_bounds__(256) k_BCS1(const uint4* __restrict__ Xb4,
                                              const int* __restrict__ rowstart,
                                              const int* __restrict__ csr,
                                              const int* __restrict__ perm,
                                              const float* __restrict__ pslot,
                                              const float* __restrict__ pgam,
                                              const float* __restrict__ pbet,
                                              const float* __restrict__ W1,
                                              const float* __restrict__ b1,
                                              const float* __restrict__ W2,
                                              const float* __restrict__ b2,
                                              unsigned* __restrict__ Outb,
                                              float* __restrict__ slot, int N) {
    __shared__ float w1s[32 * 33];
    __shared__ float w2s[32 * 33];
    __shared__ float zl[64 * 33];
    __shared__ float aa[32], cc[32], cw[32];
    __shared__ float dp1[64];
    __shared__ float redS[8][33];
    __shared__ float redQ[8][33];
    __shared__ int pl[64];
    int t = threadIdx.x;
    if (t < 32) {
        float s = 0.f, q = 0.f;
        #pragma unroll
        for (int r = 0; r < 8; r++) { s += pslot[r * 64 + t]; q += pslot[r * 64 + 32 + t]; }
        float mu = s / (float)N;
        float var = q / (float)N - mu * mu;
        float av = pgam[t] * rsqrtf(var + BN_EPS);
        aa[t] = av;
        cc[t] = pbet[t] - mu * av;
    }
    if (t >= 64 && t < 128) {
        int gid = blockIdx.x * 64 + (t - 64);
        pl[t - 64] = (gid < N) ? perm[gid] : -1;
    }
    __syncthreads();
    for (int idx = t; idx < 1024; idx += 256) {
        int k = idx >> 5, j = idx & 31;
        w1s[k * 33 + j] = aa[k] * W1[idx];
        w2s[k * 33 + j] = W2[idx];
    }
    if (t < 32) {
        float acc = 0.f;
        for (int k = 0; k < 32; k++) acc += cc[k] * W1[k * 32 + t];
        cw[t] = acc;
    }

    int g = t >> 2, l = t & 3;
    int node = pl[g];
    bool act = (node >= 0);
    int s0 = 0, s1 = 0;
    if (act) { s0 = rowstart[node]; s1 = rowstart[node + 1]; }
    float a[8] = {0.f, 0.f, 0.f, 0.f, 0.f, 0.f, 0.f, 0.f};
    if (act) addu4h(a, Xb4[(size_t)node * 4 + l]);
    int e = s0;
    for (; e + 3 < s1; e += 4) {
        int sa = csr[e], sb = csr[e + 1], sc = csr[e + 2], sd = csr[e + 3];
        uint4 va = Xb4[(size_t)sa * 4 + l];
        uint4 vb = Xb4[(size_t)sb * 4 + l];
        uint4 vc = Xb4[(size_t)sc * 4 + l];
        uint4 vd = Xb4[(size_t)sd * 4 + l];
        addu4h(a, va); addu4h(a, vb); addu4h(a, vc); addu4h(a, vd);
    }
    for (; e < s1; e++) addu4h(a, Xb4[(size_t)csr[e] * 4 + l]);
    int f0 = 8 * l;
    #pragma unroll
    for (int i = 0; i < 8; i++) zl[g * 33 + f0 + i] = a[i];
    if (l == 0) dp1[g] = (float)(s1 - s0 + 1);
    __syncthreads();

    // phase B: z-row -> t-row -> out-row in the same buffer (half-wave-exclusive rows)
    int j = t & 31, rg2 = t >> 5;
    float ps = 0.f, pq = 0.f;
    for (int rep = 0; rep < 8; rep++) {
        int n = rg2 + 8 * rep;
        float acc = dp1[n] * cw[j] + b1[j];
        #pragma unroll
        for (int k = 0; k < 32; k++) acc += zl[n * 33 + k] * w1s[k * 33 + j];
        zl[n * 33 + j] = fmaxf(acc, 0.f);
        float o = b2[j];
        #pragma unroll
        for (int k = 0; k < 32; k++) o += zl[n * 33 + k] * w2s[k * 33 + j];
        float xv = fmaxf(o, 0.f);
        zl[n * 33 + j] = xv;
        if (pl[n] >= 0) { ps += xv; pq += xv * xv; }
    }
    redS[rg2][j] = ps; redQ[rg2][j] = pq;
    __syncthreads();
    if (t < 32) {
        float s = 0.f, q = 0.f;
        #pragma unroll
        for (int r = 0; r < 8; r++) { s += redS[r][t]; q += redQ[r][t]; }
        int rep = blockIdx.x & 7;
        atomicAdd(&slot[rep * 64 + t], s);
        atomicAdd(&slot[rep * 64 + 32 + t], q);
    }
    for (int idx = t; idx < 1024; idx += 256) {
        int n = idx >> 4, jp = idx & 15;
        int nod = pl[n];
        if (nod >= 0)
            Outb[(size_t)nod * 16 + jp] = packh2(zl[n * 33 + 2 * jp], zl[n * 33 + 2 * jp + 1]);
    }
}

// pool h5 = out5*a+c per graph from fp16 out5, then xd = relu(pooled@fcxd_w+b)
__global__ void __launch_bounds__(128) k_pool(const unsigned short* __restrict__ Xb,
                                              const int* __restrict__ batch,
                                              const float* __restrict__ pslot,
                                              const float* __restrict__ pgam,
                                              const float* __restrict__ pbet,
                                              const float* __restrict__ fw,
                                              const float* __restrict__ fb,
                                              float* __restrict__ xc, int N) {
    __shared__ float red[4][32];
    __shared__ float pv[32];
    __shared__ float aa[32], cc[32];
    int g = blockIdx.x, t = threadIdx.x;
    if (t < 32) {
        float s = 0.f, q = 0.f;
        #pragma unroll
        for (int r = 0; r < 8; r++) { s += pslot[r * 64 + t]; q += pslot[r * 64 + 32 + t]; }
        float mu = s / (float)N;
        float var = q / (float)N - mu * mu;
        float av = pgam[t] * rsqrtf(var + BN_EPS);
        aa[t] = av;
        cc[t] = pbet[t] - mu * av;
    }
    int lo = lbound(batch, N, g);
    int hi = lbound(batch, N, g + 1);
    int j = t & 31, rs = t >> 5;
    float ps = 0.f;
    for (int i = lo + rs; i < hi; i += 4) ps += h2f(Xb[(size_t)i * 32 + j]);
    red[rs][j] = ps; __syncthreads();
    if (t < 32) {
        float s = red[0][t] + red[1][t] + red[2][t] + red[3][t];
        pv[t] = s * aa[t] + (float)(hi - lo) * cc[t];
    }
    __syncthreads();
    float acc = fb[t];
    for (int k = 0; k < 32; k++) acc += pv[k] * fw[k * 128 + t];
    xc[g * 256 + t] = fmaxf(acc, 0.f);
}

// ---------------- protein branch ----------------
__global__ void __launch_bounds__(128) k_F2(const float* __restrict__ Emb,
                                            const float* __restrict__ fcxt,
                                            float* __restrict__ F) {
    __shared__ float er[128];
    int bid = blockIdx.x;
    int v = bid >> 5, o = bid & 31;
    int t = threadIdx.x;
    er[t] = Emb[v * 128 + t];
    __syncthreads();
    float acc[8] = {0.f, 0.f, 0.f, 0.f, 0.f, 0.f, 0.f, 0.f};
    for (int p = 0; p < 121; p++) {
        float fv = fcxt[(o * 121 + p) * 128 + t];
        #pragma unroll
        for (int k = 0; k < 8; k++) acc[k] += er[p + k] * fv;
    }
    #pragma unroll
    for (int k = 0; k < 8; k++)
        F[((size_t)v * 256 + o * 8 + k) * 128 + t] = acc[k];
}

__global__ void __launch_bounds__(128) k_cb(const float* __restrict__ fcxt,
                                            const float* __restrict__ fb,
                                            const float* __restrict__ cb,
                                            float* __restrict__ cbias) {
    int o = blockIdx.x, t = threadIdx.x;
    float acc = 0.f;
    for (int p = 0; p < 121; p++) acc += fcxt[(o * 121 + p) * 128 + t];
    float val = cb[o] * acc;
    if (o == 0) val += fb[t];
    atomicAdd(&cbias[t], val);
}

// Dm_h[c][v][j] = fp16( sum_ok cw[o][c][kk] * F[v][ok][j] )
__global__ void __launch_bounds__(256) k_D2(const float* __restrict__ cw,
                                            const float* __restrict__ F,
                                            unsigned* __restrict__ Dmb) {
    __shared__ float Fl[32][128];
    __shared__ float Wl[32][64];
    int v = blockIdx.y;
    int c0 = blockIdx.x * 64;
    int t = threadIdx.x;
    int jg = t & 31, j0 = jg * 4;
    int cg = t >> 5;
    float4 acc[8];
    #pragma unroll
    for (int i = 0; i < 8; i++) acc[i] = make_float4(0.f, 0.f, 0.f, 0.f);
    for (int chunk = 0; chunk < 8; chunk++) {
        int k0 = chunk * 32;
        __syncthreads();
        for (int idx = t; idx < 4096; idx += 256) {
            int k = idx >> 7, j = idx & 127;
            Fl[k][j] = F[((size_t)v * 256 + k0 + k) * 128 + j];
        }
        for (int idx = t; idx < 2048; idx += 256) {
            int k = idx >> 6, c = idx & 63;
            int ok = k0 + k;
            Wl[k][c] = (c0 + c < 1000) ? cw[((ok >> 3) * 1000 + c0 + c) * 8 + (ok & 7)] : 0.f;
        }
        __syncthreads();
        for (int k = 0; k < 32; k++) {
            float4 fv = *(const float4*)&Fl[k][j0];
            #pragma unroll
            for (int ci = 0; ci < 8; ci++) {
                float wv = Wl[k][cg * 8 + ci];
                acc[ci].x += wv * fv.x;
                acc[ci].y += wv * fv.y;
                acc[ci].z += wv * fv.z;
                acc[ci].w += wv * fv.w;
            }
        }
    }
    #pragma unroll
    for (int ci = 0; ci < 8; ci++) {
        int c = c0 + cg * 8 + ci;
        if (c < 1000) {
            uint2 pk;
            pk.x = packh2(acc[ci].x, acc[ci].y);
            pk.y = packh2(acc[ci].z, acc[ci].w);
            *(uint2*)&Dmb[((size_t)c * 26 + v) * 64 + jg * 2] = pk;
        }
    }
}

// xt: one block per graph; 16 c-lanes x 16 j-lanes; no atomics
__global__ void __launch_bounds__(256) k_xt3(const int* __restrict__ target,
                                             const uint4* __restrict__ Dm4,
                                             const float* __restrict__ cbias,
                                             float* __restrict__ xc) {
    __shared__ int tl[1000];
    __shared__ float red[16][132];
    int b = blockIdx.x, t = threadIdx.x;
    for (int i = t; i < 1000; i += 256) tl[i] = target[(size_t)b * 1000 + i];
    __syncthreads();
    int cl = t >> 4;
    int jg = t & 15;
    float acc[8] = {0.f, 0.f, 0.f, 0.f, 0.f, 0.f, 0.f, 0.f};
    for (int c = cl; c < 1000; c += 16) {
        int v = tl[c];
        uint4 d = Dm4[((size_t)c * 26 + v) * 16 + jg];
        acc[0] += lo_h(d.x); acc[1] += hi_h(d.x);
        acc[2] += lo_h(d.y); acc[3] += hi_h(d.y);
        acc[4] += lo_h(d.z); acc[5] += hi_h(d.z);
        acc[6] += lo_h(d.w); acc[7] += hi_h(d.w);
    }
    #pragma unroll
    for (int fi = 0; fi < 8; fi++) red[cl][jg * 8 + fi] = acc[fi];
    __syncthreads();
    if (t < 128) {
        float s = 0.f;
        #pragma unroll
        for (int r = 0; r < 16; r++) s += red[r][t];
        xc[(size_t)b * 256 + 128 + t] = cbias[t] + s;
    }
}

// ---------------- head ----------------
__global__ void __launch_bounds__(256) k_fc1(const float* __restrict__ xc,
                                             const float* __restrict__ w,
                                             const float* __restrict__ bias,
                                             float* __restrict__ y1) {
    __shared__ float xl[16 * 256];
    int t = threadIdx.x;
    int q0 = blockIdx.x * 256, b0 = blockIdx.y * 16;
    for (int idx = t; idx < 4096; idx += 256) xl[idx] = xc[b0 * 256 + idx];
    __syncthreads();
    int ql = t & 63, q = q0 + ql * 4;
    int bg = t >> 6;
    float4 bv = *(const float4*)&bias[q];
    float4 acc0 = bv, acc1 = bv, acc2 = bv, acc3 = bv;
    const float* xr = &xl[bg * 4 * 256];
    #pragma unroll 4
    for (int k = 0; k < 256; k++) {
        float4 wv = *(const float4*)&w[k * 1024 + q];
        float x0 = xr[k], x1 = xr[256 + k], x2 = xr[512 + k], x3 = xr[768 + k];
        acc0.x += x0 * wv.x; acc0.y += x0 * wv.y; acc0.z += x0 * wv.z; acc0.w += x0 * wv.w;
        acc1.x += x1 * wv.x; acc1.y += x1 * wv.y; acc1.z += x1 * wv.z; acc1.w += x1 * wv.w;
        acc2.x += x2 * wv.x; acc2.y += x2 * wv.y; acc2.z += x2 * wv.z; acc2.w += x2 * wv.w;
        acc3.x += x3 * wv.x; acc3.y += x3 * wv.y; acc3.z += x3 * wv.z; acc3.w += x3 * wv.w;
    }
    int b = b0 + bg * 4;
    float4 r;
    r.x = fmaxf(acc0.x, 0.f); r.y = fmaxf(acc0.y, 0.f); r.z = fmaxf(acc0.z, 0.f); r.w = fmaxf(acc0.w, 0.f);
    *(float4*)&y1[(size_t)b * 1024 + q] = r;
    r.x = fmaxf(acc1.x, 0.f); r.y = fmaxf(acc1.y, 0.f); r.z = fmaxf(acc1.z, 0.f); r.w = fmaxf(acc1.w, 0.f);
    *(float4*)&y1[(size_t)(b + 1) * 1024 + q] = r;
    r.x = fmaxf(acc2.x, 0.f); r.y = fmaxf(acc2.y, 0.f); r.z = fmaxf(acc2.z, 0.f); r.w = fmaxf(acc2.w, 0.f);
    *(float4*)&y1[(size_t)(b + 2) * 1024 + q] = r;
    r.x = fmaxf(acc3.x, 0.f); r.y = fmaxf(acc3.y, 0.f); r.z = fmaxf(acc3.z, 0.f); r.w = fmaxf(acc3.w, 0.f);
    *(float4*)&y1[(size_t)(b + 3) * 1024 + q] = r;
}

__global__ void k_wcomb(const float* __restrict__ fc2w, const float* __restrict__ fc2b,
                        const float* __restrict__ ow, const float* __restrict__ ob,
                        float* __restrict__ wc) {
    int p = blockIdx.x * 256 + threadIdx.x;
    float acc = 0.f;
    for (int q = 0; q < 256; q++) acc += fc2w[p * 256 + q] * ow[q];
    wc[p] = acc;
    if (p == 0) {
        float bc = ob[0];
        for (int q = 0; q < 256; q++) bc += fc2b[q] * ow[q];
        wc[1024] = bc;
    }
}

__global__ void __launch_bounds__(256) k_out(const float* __restrict__ y1,
                                             const float* __restrict__ wc,
                                             float* __restrict__ out) {
    __shared__ float r[256];
    int b = blockIdx.x, t = threadIdx.x;
    float acc = 0.f;
    for (int p = t; p < 1024; p += 256) acc += y1[b * 1024 + p] * wc[p];
    r[t] = acc; __syncthreads();
    for (int off = 128; off > 0; off >>= 1) {
        if (t < off) r[t] += r[t + off];
        __syncthreads();
    }
    if (t == 0) out[b] = r[0] + wc[1024];
}

extern "C" void kernel_launch(void* const* d_in, const int* in_sizes, int n_in,
                              void* d_out, int out_size, void* d_ws, size_t ws_size,
                              hipStream_t stream) {
    const float* x     = (const float*)d_in[0];
    const int*   ei    = (const int*)d_in[1];
    const int*   batch = (const int*)d_in[2];
    const int*   targ  = (const int*)d_in[3];
    const float* g1w1  = (const float*)d_in[4];
    const float* g1b1  = (const float*)d_in[5];
    const float* g1w2  = (const float*)d_in[6];
    const float* g1b2  = (const float*)d_in[7];
    const float* gW1   = (const float*)d_in[8];
    const float* gb1   = (const float*)d_in[9];
    const float* gW2   = (const float*)d_in[10];
    const float* gb2   = (const float*)d_in[11];
    const float* gam   = (const float*)d_in[12];
    const float* bet   = (const float*)d_in[13];
    const float* fcxdw = (const float*)d_in[14];
    const float* fcxdb = (const float*)d_in[15];
    const float* emb   = (const float*)d_in[16];
    const float* convw = (const float*)d_in[17];
    const float* convb = (const float*)d_in[18];
    const float* fcxtw = (const float*)d_in[19];
    const float* fcxtb = (const float*)d_in[20];
    const float* fc1w  = (const float*)d_in[21];
    const float* fc1b  = (const float*)d_in[22];
    const float* fc2w  = (const float*)d_in[23];
    const float* fc2b  = (const float*)d_in[24];
    const float* outw  = (const float*)d_in[25];
    const float* outb  = (const float*)d_in[26];

    int N = in_sizes[2];
    int E = in_sizes[1] / 2;
    int B = in_sizes[3] / 1000;
    int NB = (N + 511) >> BSHIFT;

    char* ws = (char*)d_ws;
    size_t off = 0;
    auto alloc = [&](size_t bytes) -> void* {
        void* p = ws + off;
        off += (bytes + 255) & ~(size_t)255;
        return p;
    };
    int*   rowstart = (int*)alloc((size_t)(N + 1) * 4);
    int*   bbase    = (int*)alloc((NBMAX + 1) * 4);
    int*   gcur     = (int*)alloc(NBMAX * 4);
    int*   csr      = (int*)alloc((size_t)E * 4);
    int*   perm     = (int*)alloc((size_t)N * 4);
    int*   dh       = (int*)alloc(512 * 4);
    int*   dcur     = (int*)alloc(512 * 4);
    // Xb double buffer (2 x N*64B); pairs (NB*FSTRIDE*4) aliases it (dead before first Xb write)
    size_t xb_bytes = (size_t)N * 64;
    size_t pairs_bytes = (size_t)NB * FSTRIDE * 4;
    char*  blk      = (char*)alloc(2 * xb_bytes > pairs_bytes ? 2 * xb_bytes : pairs_bytes);
    unsigned* XbA   = (unsigned*)blk;
    unsigned* XbB   = (unsigned*)(blk + xb_bytes);
    int*   pairs    = (int*)blk;
    unsigned* Ub    = (unsigned*)alloc((size_t)N * 16 * 4);
    float* stats    = (float*)alloc((size_t)5 * 640 * 4);
    float* xc       = (float*)alloc((size_t)B * 256 * 4);
    float* Fb       = (float*)alloc((size_t)26 * 256 * 128 * 4);
    unsigned* Dmb   = (unsigned*)alloc((size_t)1000 * 26 * 64 * 4);
    float* cbias    = (float*)alloc(128 * 4);
    float* y1       = (float*)alloc((size_t)B * 1024 * 4);
    float* wc       = (float*)alloc(1025 * 4);

    hipMemsetAsync(gcur, 0, NBMAX * 4, stream);
    hipMemsetAsync(dh, 0, 512 * 4, stream);
    hipMemsetAsync(stats, 0, (size_t)5 * 640 * 4, stream);
    hipMemsetAsync(cbias, 0, 128 * 4, stream);

    // CSR build (chunk-sorted edge lists for L2-resident gathers)
    k_bscatter<<<(E + SCAT_CH - 1) / SCAT_CH, 256, 0, stream>>>(ei, gcur, pairs, E, NB);
    k_bscan<<<1, 512, 0, stream>>>(gcur, bbase, rowstart, N, E, NB);
    k_bfinal<<<NB, 512, 0, stream>>>(pairs, bbase, gcur, rowstart, csr, N);

    // degree-sorted node permutation (descending); two-level placement
    k_dhist<<<256, 256, 0, stream>>>(rowstart, dh, N);
    k_dscan<<<1, 512, 0, stream>>>(dh, dcur);
    k_dplace2<<<(N + DP_CH - 1) / DP_CH, 256, 0, stream>>>(rowstart, dcur, perm, N);

    int gBCS = (N + 63) / 64;

    // layer 1: out1 -> XbA, stats slot0
    k_A1<<<(N + 63) / 64, 256, 0, stream>>>(x, g1w1, Ub, N);
    k_BCS0<<<gBCS, 256, 0, stream>>>((const uint4*)Ub, rowstart, csr, perm,
                                     g1b1, g1w2, g1b2, XbA, stats, N);

    // layers 2..5
    unsigned* bufs[2] = {XbA, XbB};
    for (int i = 0; i < 4; i++) {
        unsigned* src = bufs[i & 1];
        unsigned* dst = bufs[(i + 1) & 1];
        k_BCS1<<<gBCS, 256, 0, stream>>>((const uint4*)src, rowstart, csr, perm,
                                         stats + (size_t)i * 640, gam + i * 32, bet + i * 32,
                                         gW1 + i * 1024, gb1 + i * 32,
                                         gW2 + i * 1024, gb2 + i * 32,
                                         dst, stats + (size_t)(i + 1) * 640, N);
    }
    // out5 ended in bufs[0] (XbA)

    // pooling + xd -> xc[:, 0:128]
    k_pool<<<B, 128, 0, stream>>>((const unsigned short*)XbA, batch,
                                  stats + (size_t)4 * 640, gam + 128, bet + 128,
                                  fcxdw, fcxdb, xc, N);

    // protein branch -> xc[:, 128:256]
    k_F2<<<26 * 32, 128, 0, stream>>>(emb, fcxtw, Fb);
    k_cb<<<32, 128, 0, stream>>>(fcxtw, fcxtb, convb, cbias);
    dim3 gD(16, 26);
    k_D2<<<gD, 256, 0, stream>>>(convw, Fb, Dmb);
    k_xt3<<<B, 256, 0, stream>>>(targ, (const uint4*)Dmb, cbias, xc);

    // head
    dim3 g1(4, B / 16);
    k_fc1<<<g1, 256, 0, stream>>>(xc, fc1w, fc1b, y1);
    k_wcomb<<<4, 256, 0, stream>>>(fc2w, fc2b, outw, outb, wc);
    k_out<<<B, 256, 0, stream>>>(y1, wc, (float*)d_out);
}